// Round 8
// baseline (4602.750 us; speedup 1.0000x reference)
//
#include <hip/hip_runtime.h>

#define BATCH  131072
#define NSTEPS 100

typedef _Float16 half8  __attribute__((ext_vector_type(8)));
typedef _Float16 half2t __attribute__((ext_vector_type(2)));
typedef float    f32x4  __attribute__((ext_vector_type(4)));
typedef unsigned u32x4  __attribute__((ext_vector_type(4)));

__device__ __forceinline__ unsigned pkh2(float a, float b) {
    return __builtin_bit_cast(unsigned, __builtin_amdgcn_cvt_pkrtz(a, b));
}
__device__ __forceinline__ float loh(unsigned u) {
    half2t h = __builtin_bit_cast(half2t, u); return (float)h[0];
}
__device__ __forceinline__ float hih(unsigned u) {
    half2t h = __builtin_bit_cast(half2t, u); return (float)h[1];
}

// ---------------------------------------------------------------------------
// R7 structure (shared read-only weights in LDS, activations in registers),
// with the scratch-spill trigger removed: NO address-taken local arrays in
// the hot loop. L0 coeff words are read straight from LDS at use sites
// (broadcast ds_reads); bias/W4 are direct LDS f32x4 reads. Register peak
// ~110 -> fits 128-cap of __launch_bounds__(256,4), 4 waves/SIMD, no spill.
//
// Wave owns 16 samples; lane (c=l&15, g=l>>4). k-slot convention: B-frag
// (kt,qq,r) holds neuron n = 32kt+16qq+4g+r; C layout row = 16mt+4g+r makes
// lane g's C-quads exactly its next-layer B-frags. A-frags use the same
// k-permutation, so the contraction is invariant (numerics verified R5-R7).
// ---------------------------------------------------------------------------
extern "C" __global__ void __launch_bounds__(256, 4)
fbsnn_kernel(const float* __restrict__ W0, const float* __restrict__ b0,
             const float* __restrict__ W1, const float* __restrict__ b1,
             const float* __restrict__ W2, const float* __restrict__ b2,
             const float* __restrict__ W3, const float* __restrict__ b3,
             const float* __restrict__ W4, const float* __restrict__ b4,
             const float* __restrict__ y0p, const float* __restrict__ dW,
             float* __restrict__ slots)
{
    __shared__ unsigned ldsA[6144];    // 24576 B: A-frags, u32-packed f16 pairs
    __shared__ unsigned ldsL0[96];     // wa[32] | wb[32] | b[32]  (half2-packed)
    __shared__ float    ldsBias[192];  // [li][mt][g][r]
    __shared__ float    ldsW4[64];     // [mt][g][r]

    const int tid = threadIdx.x;
    const int l   = tid & 63;
    const int wu  = tid >> 6;
    const int c   = l & 15;
    const int g   = l >> 4;
    const int sample = blockIdx.x * 64 + wu * 16 + c;

    const float DT = 0.01f, SQDT = 0.1f;

    // ================= prep: stage weights into LDS =================
    {
        for (int idx = tid; idx < 6144; idx += 256) {
            int w   = idx & 3;          // word within 16B lane chunk
            int lam = (idx >> 2) & 63;  // lane
            int f   = (idx >> 8) & 7;   // frag = mt*2 + kt
            int li  = idx >> 11;        // layer
            const float* Wsl = (li == 0) ? W1 : (li == 1) ? W2 : W3;
            int cc = lam & 15, gg = lam >> 4;
            int mt = f >> 1, kt = f & 1;
            int m = 16 * mt + cc;
            int k = 32 * kt + 16 * (w >> 1) + 4 * gg + ((2 * w) & 3);
            const float* Wp = Wsl + m * 64 + k;
            ldsA[(8 * li + f) * 256 + lam * 4 + w] = pkh2(Wp[0], Wp[1]);
        }
        if (tid < 32) {
            int gg = tid >> 3, qi = (tid >> 1) & 3, h = tid & 1;
            int n0 = 32 * (qi >> 1) + 16 * (qi & 1) + 4 * gg + 2 * h;
            int o  = gg * 8 + qi * 2 + h;
            ldsL0[o]      = pkh2(W0[2 * n0],     W0[2 * n0 + 2]);
            ldsL0[32 + o] = pkh2(W0[2 * n0 + 1], W0[2 * n0 + 3]);
            ldsL0[64 + o] = pkh2(b0[n0],         b0[n0 + 1]);
        }
        if (tid < 192) {
            int li = tid >> 6, mt = (tid >> 4) & 3, gg = (tid >> 2) & 3, r = tid & 3;
            ldsBias[tid] = ((li == 0) ? b1 : (li == 1) ? b2 : b3)[16 * mt + 4 * gg + r];
        }
        if (tid < 64) {
            int mt = tid >> 4, gg = (tid >> 2) & 3, r = tid & 3;
            ldsW4[tid] = W4[16 * mt + 4 * gg + r];
        }
    }
    __syncthreads();   // only barrier; LDS is read-only below

    const float b4v = b4[0];
    float y = y0p[0];
    float t = 0.0f;
    float Y0 = 0.f, dY0 = 0.f, q0 = 0.f, Z0 = 0.f, dws = 0.f, loss = 0.f;

    #pragma unroll 1
    for (int s = 0; s <= NSTEPS; ++s) {
        float dwv = 0.0f;
        if (s < NSTEPS) dwv = dW[s * BATCH + sample];   // prefetch early

        // ============ layer 0: build B-frags in registers ============
        // coeff words read DIRECTLY from LDS (no local staging arrays!)
        half8 BX[2], BV[2];
        #pragma unroll
        for (int kt = 0; kt < 2; ++kt) {
            u32x4 ux, uv;
            #pragma unroll
            for (int qq = 0; qq < 2; ++qq) {
                int qi = 2 * kt + qq;
                float sn[4], vv[4];
                #pragma unroll
                for (int h = 0; h < 2; ++h) {
                    int o = g * 8 + qi * 2 + h;
                    unsigned uwa = ldsL0[o];
                    unsigned uwb = ldsL0[32 + o];
                    unsigned ubb = ldsL0[64 + o];
                    float wa0 = loh(uwa), wa1 = hih(uwa);
                    float wb0 = loh(uwb), wb1 = hih(uwb);
                    float c00 = loh(ubb), c01 = hih(ubb);
                    float z0 = fmaf(wa0, t, fmaf(wb0, y, c00));
                    float z1 = fmaf(wa1, t, fmaf(wb1, y, c01));
                    float s0, cc0, s1, cc1;
                    __sincosf(z0, &s0, &cc0);
                    __sincosf(z1, &s1, &cc1);
                    sn[2 * h] = s0; sn[2 * h + 1] = s1;
                    vv[2 * h] = cc0 * wb0; vv[2 * h + 1] = cc1 * wb1;
                }
                ux[2 * qq + 0] = pkh2(sn[0], sn[1]);
                ux[2 * qq + 1] = pkh2(sn[2], sn[3]);
                uv[2 * qq + 0] = pkh2(vv[0], vv[1]);
                uv[2 * qq + 1] = pkh2(vv[2], vv[3]);
            }
            BX[kt] = __builtin_bit_cast(half8, ux);
            BV[kt] = __builtin_bit_cast(half8, uv);
        }

        // ============ hidden layers 1..3 ============
        float Y1 = 0.f, dY1 = 0.f;
        #pragma unroll
        for (int li = 0; li < 3; ++li) {
            f32x4 ax[4], av[4];
            #pragma unroll
            for (int mt = 0; mt < 4; ++mt) {
                half8 a0 = *(const half8*)&ldsA[(8 * li + 2 * mt + 0) * 256 + l * 4];
                half8 a1 = *(const half8*)&ldsA[(8 * li + 2 * mt + 1) * 256 + l * 4];
                f32x4 ci = *(const f32x4*)&ldsBias[((li * 4 + mt) * 4 + g) * 4];
                f32x4 a = __builtin_amdgcn_mfma_f32_16x16x32_f16(a0, BX[0], ci, 0, 0, 0);
                a = __builtin_amdgcn_mfma_f32_16x16x32_f16(a1, BX[1], a, 0, 0, 0);
                ax[mt] = a;
                f32x4 v = {0.f, 0.f, 0.f, 0.f};
                v = __builtin_amdgcn_mfma_f32_16x16x32_f16(a0, BV[0], v, 0, 0, 0);
                v = __builtin_amdgcn_mfma_f32_16x16x32_f16(a1, BV[1], v, 0, 0, 0);
                av[mt] = v;
            }
            if (li < 2) {
                u32x4 nx[2], nv[2];
                #pragma unroll
                for (int mt = 0; mt < 4; ++mt) {
                    float sn[4], vv[4];
                    #pragma unroll
                    for (int r = 0; r < 4; ++r) {
                        float s1, c1;
                        __sincosf(ax[mt][r], &s1, &c1);
                        sn[r] = s1; vv[r] = c1 * av[mt][r];
                    }
                    nx[mt >> 1][2 * (mt & 1) + 0] = pkh2(sn[0], sn[1]);
                    nx[mt >> 1][2 * (mt & 1) + 1] = pkh2(sn[2], sn[3]);
                    nv[mt >> 1][2 * (mt & 1) + 0] = pkh2(vv[0], vv[1]);
                    nv[mt >> 1][2 * (mt & 1) + 1] = pkh2(vv[2], vv[3]);
                }
                BX[0] = __builtin_bit_cast(half8, nx[0]);
                BX[1] = __builtin_bit_cast(half8, nx[1]);
                BV[0] = __builtin_bit_cast(half8, nv[0]);
                BV[1] = __builtin_bit_cast(half8, nv[1]);
            } else {
                float sx = 0.f, sv = 0.f;
                #pragma unroll
                for (int mt = 0; mt < 4; ++mt) {
                    f32x4 wv4 = *(const f32x4*)&ldsW4[(mt * 4 + g) * 4];
                    #pragma unroll
                    for (int r = 0; r < 4; ++r) {
                        float s1, c1;
                        __sincosf(ax[mt][r], &s1, &c1);
                        sx = fmaf(wv4[r], s1, sx);
                        sv = fmaf(wv4[r], c1 * av[mt][r], sv);
                    }
                }
                sx += __shfl_xor(sx, 16); sx += __shfl_xor(sx, 32);
                sv += __shfl_xor(sv, 16); sv += __shfl_xor(sv, 32);
                Y1  = sx + b4v;
                dY1 = sv;
            }
        }

        // ============ trajectory / loss ============
        if (s > 0) {
            float Yt = Y0 - q0 * q0 * DT + Z0 * dws;
            float d  = Y1 - Yt;
            loss += d * d;
        }
        Y0 = Y1; dY0 = dY1;
        if (s < NSTEPS) {
            Z0  = 0.5f * dY0;
            q0  = -dY0;                 // exact (power-of-2 constants)
            dws = dwv * SQDT;
            y   = y + q0 * DT + 0.5f * dws;
            t   = t + DT;
        }
    }

    // terminal: (YN - yN^2)^2 + (dYN - 2*yN)^2
    float d1 = Y0 - y * y;
    float d2 = dY0 - 2.0f * y;
    loss += d1 * d1 + d2 * d2;

    // 4 g-lanes share a sample -> mask, then wave butterfly
    float lv = (g == 0) ? loss : 0.0f;
    #pragma unroll
    for (int off = 1; off < 64; off <<= 1)
        lv += __shfl_xor(lv, off);
    if (l == 0)
        atomicAdd(&slots[(blockIdx.x * 4 + wu) & 255], lv);
}

extern "C" __global__ void finish_kernel(const float* __restrict__ slots,
                                         float* __restrict__ out) {
    int l = threadIdx.x;   // 64 threads
    float v = slots[l] + slots[64 + l] + slots[128 + l] + slots[192 + l];
    #pragma unroll
    for (int off = 1; off < 64; off <<= 1)
        v += __shfl_xor(v, off);
    if (l == 0) out[0] = v * (1.0f / (float)BATCH);
}

extern "C" void kernel_launch(void* const* d_in, const int* in_sizes, int n_in,
                              void* d_out, int out_size, void* d_ws, size_t ws_size,
                              hipStream_t stream) {
    const float* W0  = (const float*)d_in[0];
    const float* b0  = (const float*)d_in[1];
    const float* W1  = (const float*)d_in[2];
    const float* b1  = (const float*)d_in[3];
    const float* W2  = (const float*)d_in[4];
    const float* b2  = (const float*)d_in[5];
    const float* W3  = (const float*)d_in[6];
    const float* b3  = (const float*)d_in[7];
    const float* W4  = (const float*)d_in[8];
    const float* b4  = (const float*)d_in[9];
    const float* y0p = (const float*)d_in[10];
    const float* dW  = (const float*)d_in[11];
    float* slots = (float*)d_ws;

    hipMemsetAsync(d_ws, 0, 256 * sizeof(float), stream);

    dim3 grid(BATCH / 64);   // 2048 blocks x 4 independent waves (16 samples)
    dim3 block(256);
    fbsnn_kernel<<<grid, block, 0, stream>>>(W0, b0, W1, b1, W2, b2, W3, b3,
                                             W4, b4, y0p, dW, slots);
    finish_kernel<<<1, 64, 0, stream>>>(slots, (float*)d_out);
}

// Round 9
// 942.065 us; speedup vs baseline: 4.8858x; 4.8858x over previous
//
#include <hip/hip_runtime.h>

#define BATCH  131072
#define NSTEPS 100

typedef _Float16 half8  __attribute__((ext_vector_type(8)));
typedef _Float16 half2t __attribute__((ext_vector_type(2)));
typedef float    f32x4  __attribute__((ext_vector_type(4)));
typedef unsigned u32x4  __attribute__((ext_vector_type(4)));

__device__ __forceinline__ unsigned pkh2(float a, float b) {
    return __builtin_bit_cast(unsigned, __builtin_amdgcn_cvt_pkrtz(a, b));
}
__device__ __forceinline__ float loh(unsigned u) {
    half2t h = __builtin_bit_cast(half2t, u); return (float)h[0];
}
__device__ __forceinline__ float hih(unsigned u) {
    half2t h = __builtin_bit_cast(half2t, u); return (float)h[1];
}

// ---------------------------------------------------------------------------
// R7/R8 structure (shared read-only weights staged once in LDS; activations
// pure-register; barrier-free main loop). ONE change vs R8:
// __launch_bounds__(256, 2) instead of (256, 4).
//
// Why: gfx950's unified VGPR/AGPR file means the (256,4) bound capped TOTAL
// regs at 128/wave (64 arch + 64 acc per rocprof) while demand is ~160-180;
// the allocator spilled ~180 dwords of loop-invariant state to scratch,
// re-read every step => 17 GB/dispatch HBM reads (R7/R8's 4.6 ms). With a
// 256 cap the demand fits (~160 total) with zero spill, and the HW still
// runs 3 waves/SIMD = floor(512/~170) -- better than R6's 2 waves/SIMD.
//
// Wave owns 16 samples; lane (c=l&15, g=l>>4). k-slot convention: B-frag
// (kt,qq,r) holds neuron n = 32kt+16qq+4g+r; C layout row = 16mt+4g+r makes
// lane g's C-quads exactly its next-layer B-frags. A-frags use the same
// k-permutation, so the contraction is invariant (numerics verified R5-R8).
// ---------------------------------------------------------------------------
extern "C" __global__ void __launch_bounds__(256, 2)
fbsnn_kernel(const float* __restrict__ W0, const float* __restrict__ b0,
             const float* __restrict__ W1, const float* __restrict__ b1,
             const float* __restrict__ W2, const float* __restrict__ b2,
             const float* __restrict__ W3, const float* __restrict__ b3,
             const float* __restrict__ W4, const float* __restrict__ b4,
             const float* __restrict__ y0p, const float* __restrict__ dW,
             float* __restrict__ slots)
{
    __shared__ unsigned ldsA[6144];    // 24576 B: A-frags, u32-packed f16 pairs
    __shared__ unsigned ldsL0[96];     // wa[32] | wb[32] | b[32]  (half2-packed)
    __shared__ float    ldsBias[192];  // [li][mt][g][r]
    __shared__ float    ldsW4[64];     // [mt][g][r]

    const int tid = threadIdx.x;
    const int l   = tid & 63;
    const int wu  = tid >> 6;
    const int c   = l & 15;
    const int g   = l >> 4;
    const int sample = blockIdx.x * 64 + wu * 16 + c;

    const float DT = 0.01f, SQDT = 0.1f;

    // ================= prep: stage weights into LDS =================
    {
        for (int idx = tid; idx < 6144; idx += 256) {
            int w   = idx & 3;          // word within 16B lane chunk
            int lam = (idx >> 2) & 63;  // lane
            int f   = (idx >> 8) & 7;   // frag = mt*2 + kt
            int li  = idx >> 11;        // layer
            const float* Wsl = (li == 0) ? W1 : (li == 1) ? W2 : W3;
            int cc = lam & 15, gg = lam >> 4;
            int mt = f >> 1, kt = f & 1;
            int m = 16 * mt + cc;
            int k = 32 * kt + 16 * (w >> 1) + 4 * gg + ((2 * w) & 3);
            const float* Wp = Wsl + m * 64 + k;
            ldsA[(8 * li + f) * 256 + lam * 4 + w] = pkh2(Wp[0], Wp[1]);
        }
        if (tid < 32) {
            int gg = tid >> 3, qi = (tid >> 1) & 3, h = tid & 1;
            int n0 = 32 * (qi >> 1) + 16 * (qi & 1) + 4 * gg + 2 * h;
            int o  = gg * 8 + qi * 2 + h;
            ldsL0[o]      = pkh2(W0[2 * n0],     W0[2 * n0 + 2]);
            ldsL0[32 + o] = pkh2(W0[2 * n0 + 1], W0[2 * n0 + 3]);
            ldsL0[64 + o] = pkh2(b0[n0],         b0[n0 + 1]);
        }
        if (tid < 192) {
            int li = tid >> 6, mt = (tid >> 4) & 3, gg = (tid >> 2) & 3, r = tid & 3;
            ldsBias[tid] = ((li == 0) ? b1 : (li == 1) ? b2 : b3)[16 * mt + 4 * gg + r];
        }
        if (tid < 64) {
            int mt = tid >> 4, gg = (tid >> 2) & 3, r = tid & 3;
            ldsW4[tid] = W4[16 * mt + 4 * gg + r];
        }
    }
    __syncthreads();   // only barrier; LDS is read-only below

    const float b4v = b4[0];
    float y = y0p[0];
    float t = 0.0f;
    float Y0 = 0.f, dY0 = 0.f, q0 = 0.f, Z0 = 0.f, dws = 0.f, loss = 0.f;

    #pragma unroll 1
    for (int s = 0; s <= NSTEPS; ++s) {
        float dwv = 0.0f;
        if (s < NSTEPS) dwv = dW[s * BATCH + sample];   // prefetch early

        // ============ layer 0: build B-frags in registers ============
        half8 BX[2], BV[2];
        #pragma unroll
        for (int kt = 0; kt < 2; ++kt) {
            u32x4 ux, uv;
            #pragma unroll
            for (int qq = 0; qq < 2; ++qq) {
                int qi = 2 * kt + qq;
                float sn[4], vv[4];
                #pragma unroll
                for (int h = 0; h < 2; ++h) {
                    int o = g * 8 + qi * 2 + h;
                    unsigned uwa = ldsL0[o];
                    unsigned uwb = ldsL0[32 + o];
                    unsigned ubb = ldsL0[64 + o];
                    float wa0 = loh(uwa), wa1 = hih(uwa);
                    float wb0 = loh(uwb), wb1 = hih(uwb);
                    float c00 = loh(ubb), c01 = hih(ubb);
                    float z0 = fmaf(wa0, t, fmaf(wb0, y, c00));
                    float z1 = fmaf(wa1, t, fmaf(wb1, y, c01));
                    float s0, cc0, s1, cc1;
                    __sincosf(z0, &s0, &cc0);
                    __sincosf(z1, &s1, &cc1);
                    sn[2 * h] = s0; sn[2 * h + 1] = s1;
                    vv[2 * h] = cc0 * wb0; vv[2 * h + 1] = cc1 * wb1;
                }
                ux[2 * qq + 0] = pkh2(sn[0], sn[1]);
                ux[2 * qq + 1] = pkh2(sn[2], sn[3]);
                uv[2 * qq + 0] = pkh2(vv[0], vv[1]);
                uv[2 * qq + 1] = pkh2(vv[2], vv[3]);
            }
            BX[kt] = __builtin_bit_cast(half8, ux);
            BV[kt] = __builtin_bit_cast(half8, uv);
        }

        // ============ hidden layers 1..3 ============
        float Y1 = 0.f, dY1 = 0.f;
        #pragma unroll
        for (int li = 0; li < 3; ++li) {
            f32x4 ax[4], av[4];
            #pragma unroll
            for (int mt = 0; mt < 4; ++mt) {
                half8 a0 = *(const half8*)&ldsA[(8 * li + 2 * mt + 0) * 256 + l * 4];
                half8 a1 = *(const half8*)&ldsA[(8 * li + 2 * mt + 1) * 256 + l * 4];
                f32x4 ci = *(const f32x4*)&ldsBias[((li * 4 + mt) * 4 + g) * 4];
                f32x4 a = __builtin_amdgcn_mfma_f32_16x16x32_f16(a0, BX[0], ci, 0, 0, 0);
                a = __builtin_amdgcn_mfma_f32_16x16x32_f16(a1, BX[1], a, 0, 0, 0);
                ax[mt] = a;
                f32x4 v = {0.f, 0.f, 0.f, 0.f};
                v = __builtin_amdgcn_mfma_f32_16x16x32_f16(a0, BV[0], v, 0, 0, 0);
                v = __builtin_amdgcn_mfma_f32_16x16x32_f16(a1, BV[1], v, 0, 0, 0);
                av[mt] = v;
            }
            if (li < 2) {
                u32x4 nx[2], nv[2];
                #pragma unroll
                for (int mt = 0; mt < 4; ++mt) {
                    float sn[4], vv[4];
                    #pragma unroll
                    for (int r = 0; r < 4; ++r) {
                        float s1, c1;
                        __sincosf(ax[mt][r], &s1, &c1);
                        sn[r] = s1; vv[r] = c1 * av[mt][r];
                    }
                    nx[mt >> 1][2 * (mt & 1) + 0] = pkh2(sn[0], sn[1]);
                    nx[mt >> 1][2 * (mt & 1) + 1] = pkh2(sn[2], sn[3]);
                    nv[mt >> 1][2 * (mt & 1) + 0] = pkh2(vv[0], vv[1]);
                    nv[mt >> 1][2 * (mt & 1) + 1] = pkh2(vv[2], vv[3]);
                }
                BX[0] = __builtin_bit_cast(half8, nx[0]);
                BX[1] = __builtin_bit_cast(half8, nx[1]);
                BV[0] = __builtin_bit_cast(half8, nv[0]);
                BV[1] = __builtin_bit_cast(half8, nv[1]);
            } else {
                float sx = 0.f, sv = 0.f;
                #pragma unroll
                for (int mt = 0; mt < 4; ++mt) {
                    f32x4 wv4 = *(const f32x4*)&ldsW4[(mt * 4 + g) * 4];
                    #pragma unroll
                    for (int r = 0; r < 4; ++r) {
                        float s1, c1;
                        __sincosf(ax[mt][r], &s1, &c1);
                        sx = fmaf(wv4[r], s1, sx);
                        sv = fmaf(wv4[r], c1 * av[mt][r], sv);
                    }
                }
                sx += __shfl_xor(sx, 16); sx += __shfl_xor(sx, 32);
                sv += __shfl_xor(sv, 16); sv += __shfl_xor(sv, 32);
                Y1  = sx + b4v;
                dY1 = sv;
            }
        }

        // ============ trajectory / loss ============
        if (s > 0) {
            float Yt = Y0 - q0 * q0 * DT + Z0 * dws;
            float d  = Y1 - Yt;
            loss += d * d;
        }
        Y0 = Y1; dY0 = dY1;
        if (s < NSTEPS) {
            Z0  = 0.5f * dY0;
            q0  = -dY0;                 // exact (power-of-2 constants)
            dws = dwv * SQDT;
            y   = y + q0 * DT + 0.5f * dws;
            t   = t + DT;
        }
    }

    // terminal: (YN - yN^2)^2 + (dYN - 2*yN)^2
    float d1 = Y0 - y * y;
    float d2 = dY0 - 2.0f * y;
    loss += d1 * d1 + d2 * d2;

    // 4 g-lanes share a sample -> mask, then wave butterfly
    float lv = (g == 0) ? loss : 0.0f;
    #pragma unroll
    for (int off = 1; off < 64; off <<= 1)
        lv += __shfl_xor(lv, off);
    if (l == 0)
        atomicAdd(&slots[(blockIdx.x * 4 + wu) & 255], lv);
}

extern "C" __global__ void finish_kernel(const float* __restrict__ slots,
                                         float* __restrict__ out) {
    int l = threadIdx.x;   // 64 threads
    float v = slots[l] + slots[64 + l] + slots[128 + l] + slots[192 + l];
    #pragma unroll
    for (int off = 1; off < 64; off <<= 1)
        v += __shfl_xor(v, off);
    if (l == 0) out[0] = v * (1.0f / (float)BATCH);
}

extern "C" void kernel_launch(void* const* d_in, const int* in_sizes, int n_in,
                              void* d_out, int out_size, void* d_ws, size_t ws_size,
                              hipStream_t stream) {
    const float* W0  = (const float*)d_in[0];
    const float* b0  = (const float*)d_in[1];
    const float* W1  = (const float*)d_in[2];
    const float* b1  = (const float*)d_in[3];
    const float* W2  = (const float*)d_in[4];
    const float* b2  = (const float*)d_in[5];
    const float* W3  = (const float*)d_in[6];
    const float* b3  = (const float*)d_in[7];
    const float* W4  = (const float*)d_in[8];
    const float* b4  = (const float*)d_in[9];
    const float* y0p = (const float*)d_in[10];
    const float* dW  = (const float*)d_in[11];
    float* slots = (float*)d_ws;

    hipMemsetAsync(d_ws, 0, 256 * sizeof(float), stream);

    dim3 grid(BATCH / 64);   // 2048 blocks x 4 independent waves (16 samples)
    dim3 block(256);
    fbsnn_kernel<<<grid, block, 0, stream>>>(W0, b0, W1, b1, W2, b2, W3, b3,
                                             W4, b4, y0p, dW, slots);
    finish_kernel<<<1, 64, 0, stream>>>(slots, (float*)d_out);
}